// Round 1
// baseline (1123.097 us; speedup 1.0000x reference)
//
#include <hip/hip_runtime.h>
#include <math.h>

#define NN 10000
#define NE 100000
#define CC 6
#define LL 6
#define BB 16
#define FUNC_LO 100
#define FUNC_HI 9900
#define NOUT 100
#define EPSF 1e-5f

__device__ __forceinline__ float eluf(float x){ return x > 0.0f ? x : expm1f(x); }

// Zero counters, init z3 = b3 broadcast (non-selected edges keep this forever),
// transpose x (B,N) -> xT (N,B).
__global__ void k_setup(int* __restrict__ counts, int* __restrict__ fill,
                        double* __restrict__ sums, float* __restrict__ z3,
                        const float* __restrict__ b3,
                        const float* __restrict__ x, float* __restrict__ xT){
  int tid = blockIdx.x*blockDim.x + threadIdx.x;
  int nt  = gridDim.x*blockDim.x;
  for(int i=tid;i<NN;i+=nt){ counts[i]=0; fill[i]=0; }
  if(tid < 2*LL + 2) sums[tid] = 0.0;
  for(int i=tid;i<NE*BB;i+=nt) z3[i] = b3[i>>4];
  for(int i=tid;i<NN*BB;i+=nt){ int n=i>>4, b=i&15; xT[i] = x[b*NN + n]; }
}

// Histogram of dst; also accumulate BN-sum contribution of non-selected edges
// (src not a func node): z3 stays b3[e] for those, constant across layers.
__global__ void k_count(const int* __restrict__ dst, int* __restrict__ counts,
                        const int* __restrict__ src, const float* __restrict__ b3,
                        double* __restrict__ base){
  int e = blockIdx.x*blockDim.x + threadIdx.x;
  if(e >= NE) return;
  atomicAdd(&counts[dst[e]], 1);
  int s = src[e];
  if(!(s >= FUNC_LO && s < FUNC_HI)){
    float v = b3[e];
    atomicAdd(&base[0], (double)v * BB);
    atomicAdd(&base[1], (double)v * (double)v * BB);
  }
}

// Single-block exclusive scan over counts (N=10000), chunked Hillis-Steele.
__global__ void k_scan(const int* __restrict__ counts, int* __restrict__ row_start){
  __shared__ int lds[1024];
  __shared__ int carry;
  if(threadIdx.x==0) carry = 0;
  __syncthreads();
  for(int base=0; base<NN; base+=1024){
    int i = base + (int)threadIdx.x;
    int v = (i<NN) ? counts[i] : 0;
    lds[threadIdx.x] = v; __syncthreads();
    for(int off=1; off<1024; off<<=1){
      int t = (threadIdx.x>=off) ? lds[threadIdx.x-off] : 0;
      __syncthreads();
      lds[threadIdx.x] += t;
      __syncthreads();
    }
    int incl = lds[threadIdx.x];
    if(i<NN) row_start[i] = carry + incl - v;
    __syncthreads();
    if(threadIdx.x==1023) carry += lds[1023];
    __syncthreads();
  }
  if(threadIdx.x==0) row_start[NN] = carry;
}

__global__ void k_fill(const int* __restrict__ dst, const int* __restrict__ row_start,
                       int* __restrict__ fill, int* __restrict__ csr){
  int e = blockIdx.x*blockDim.x + threadIdx.x;
  if(e >= NE) return;
  int n = dst[e];
  int p = row_start[n] + atomicAdd(&fill[n], 1);
  csr[p] = e;
}

// h[e][b] = x[b][src[e]]  (via transposed xT for coalescing)
__global__ void k_hinit(const int* __restrict__ src, const float* __restrict__ xT,
                        float* __restrict__ h){
  int idx = blockIdx.x*blockDim.x + threadIdx.x;
  if(idx >= NE*BB) return;
  int e = idx>>4, b = idx&15;
  h[idx] = xT[src[e]*BB + b];
}

// Fused: z1 = CSR-gather(h)*W1 + b1 ; ELU ; z2 = z1 * W2block + b2 ; ELU.
// One 16-lane group per func node; lane = batch index. z1 lives in registers.
__global__ __launch_bounds__(256) void k_layerA(
    const float* __restrict__ h, const int* __restrict__ row_start,
    const int* __restrict__ counts, const int* __restrict__ csr,
    const float* __restrict__ w1v, const float* __restrict__ b1,
    const int* __restrict__ w2r, const float* __restrict__ w2v,
    const float* __restrict__ b2, float* __restrict__ z2f, int F){
  int t = blockIdx.x*256 + (int)threadIdx.x;
  int fi = t>>4, b = t&15;
  if(fi >= F) return;
  int n = w2r[fi*36] / CC;   // func node id from w2 structure
  float acc[CC];
  #pragma unroll
  for(int i=0;i<CC;i++) acc[i] = b1[n*CC+i];
  int beg = row_start[n], end = beg + counts[n];
  for(int p=beg; p<end; ++p){
    int e = csr[p];
    float hv = h[e*BB + b];
    const float* w = &w1v[e*CC];
    #pragma unroll
    for(int i=0;i<CC;i++) acc[i] += hv * w[i];
  }
  #pragma unroll
  for(int i=0;i<CC;i++) acc[i] = eluf(acc[i]);
  const float* W2 = &w2v[fi*36];
  #pragma unroll
  for(int j=0;j<CC;j++){
    float o = b2[n*CC+j];
    #pragma unroll
    for(int i=0;i<CC;i++) o += acc[i] * W2[i*CC + j];
    z2f[(fi*CC + j)*BB + b] = eluf(o);
  }
}

// z3[e] = b3[e] + sum_i z2f[src-block] * w3 ; accumulate BN partial sums.
__global__ __launch_bounds__(256) void k_layerB(
    const float* __restrict__ z2f, const int* __restrict__ w3r,
    const int* __restrict__ w3c, const float* __restrict__ w3v,
    const float* __restrict__ b3, float* __restrict__ z3,
    double* __restrict__ sums, int Ksel){
  int t = blockIdx.x*256 + (int)threadIdx.x;
  int k = t>>4, b = t&15;
  float val = 0.0f;
  if(k < Ksel){
    int e = w3c[k*CC];
    int s = w3r[k*CC] / CC;
    int fi = s - FUNC_LO;
    float o = b3[e];
    #pragma unroll
    for(int i=0;i<CC;i++) o += z2f[(fi*CC + i)*BB + b] * w3v[k*CC + i];
    z3[e*BB + b] = o;
    val = o;
  }
  float s1 = val, s2 = val*val;
  for(int off=32; off; off>>=1){ s1 += __shfl_down(s1, off); s2 += __shfl_down(s2, off); }
  __shared__ float r1[4], r2[4];
  int wid = threadIdx.x>>6;
  if((threadIdx.x & 63)==0){ r1[wid]=s1; r2[wid]=s2; }
  __syncthreads();
  if(threadIdx.x==0){
    float a = r1[0]+r1[1]+r1[2]+r1[3];
    float q = r2[0]+r2[1]+r2[2]+r2[3];
    atomicAdd(&sums[0], (double)a);
    atomicAdd(&sums[1], (double)q);
  }
}

// BN normalize + residual, in place on h.
__global__ void k_layerD(const float* __restrict__ z3, float* __restrict__ h,
                         const double* __restrict__ sums, const double* __restrict__ base,
                         const float* __restrict__ gamma, const float* __restrict__ beta, int l){
  int idx = blockIdx.x*blockDim.x + threadIdx.x;
  if(idx >= NE*BB) return;
  double S  = sums[0] + base[0];
  double SS = sums[1] + base[1];
  const double cnt = (double)NE * (double)BB;
  double md = S / cnt;
  double vd = SS / cnt - md*md;
  float m   = (float)md;
  float inv = (float)(1.0 / sqrt(vd + (double)EPSF));
  float g = gamma[l], be = beta[l];
  h[idx] += (z3[idx] - m) * inv * g + be;
}

__global__ void k_outzero(float* __restrict__ out){
  int idx = blockIdx.x*blockDim.x + threadIdx.x;
  if(idx < BB*NN) out[idx] = 0.0f;
}

// out[b][n] = (sum over in-edges of h)/L for output nodes n in [9900,10000).
__global__ void k_outscatter(const float* __restrict__ h, const int* __restrict__ row_start,
                             const int* __restrict__ counts, const int* __restrict__ csr,
                             float* __restrict__ out){
  int t = blockIdx.x*blockDim.x + threadIdx.x;
  if(t >= NOUT*BB) return;
  int g = t>>4, b = t&15;
  int n = FUNC_HI + g;
  float acc = 0.0f;
  int beg = row_start[n], end = beg + counts[n];
  for(int p=beg; p<end; ++p) acc += h[csr[p]*BB + b];
  out[b*NN + n] = acc * (1.0f/(float)LL);
}

extern "C" void kernel_launch(void* const* d_in, const int* in_sizes, int n_in,
                              void* d_out, int out_size, void* d_ws, size_t ws_size,
                              hipStream_t stream){
  const float* x    = (const float*)d_in[0];
  const int*   src  = (const int*)  d_in[1];
  const int*   dst  = (const int*)  d_in[2];
  const float* w1v  = (const float*)d_in[6];
  const float* b1   = (const float*)d_in[7];
  const int*   w2r  = (const int*)  d_in[8];
  const float* w2v  = (const float*)d_in[10];
  const float* b2   = (const float*)d_in[11];
  const int*   w3r  = (const int*)  d_in[12];
  const int*   w3c  = (const int*)  d_in[13];
  const float* w3v  = (const float*)d_in[14];
  const float* b3   = (const float*)d_in[15];
  const float* gamma= (const float*)d_in[16];
  const float* beta = (const float*)d_in[17];
  int F    = in_sizes[8]  / 36;
  int Ksel = in_sizes[12] / CC;

  char* ws = (char*)d_ws;
  size_t off = 0;
  auto alloc = [&](size_t bytes)->char*{
    char* p = ws + off;
    off = (off + bytes + 255) & ~(size_t)255;
    return p;
  };
  int*    row_start = (int*)   alloc((NN+1)*sizeof(int));
  int*    counts    = (int*)   alloc(NN*sizeof(int));
  int*    fill      = (int*)   alloc(NN*sizeof(int));
  int*    csr       = (int*)   alloc(NE*sizeof(int));
  float*  xT        = (float*) alloc((size_t)NN*BB*sizeof(float));
  float*  h         = (float*) alloc((size_t)NE*BB*sizeof(float));
  float*  z2f       = (float*) alloc((size_t)F*CC*BB*sizeof(float));
  float*  z3        = (float*) alloc((size_t)NE*BB*sizeof(float));
  double* sums      = (double*)alloc((2*LL+2)*sizeof(double));
  (void)ws_size; (void)n_in; (void)out_size;

  k_setup<<<1024,256,0,stream>>>(counts,fill,sums,z3,b3,x,xT);
  k_count<<<(NE+255)/256,256,0,stream>>>(dst,counts,src,b3,sums+2*LL);
  k_scan<<<1,1024,0,stream>>>(counts,row_start);
  k_fill<<<(NE+255)/256,256,0,stream>>>(dst,row_start,fill,csr);
  k_hinit<<<(NE*BB+255)/256,256,0,stream>>>(src,xT,h);

  for(int l=0;l<LL;l++){
    k_layerA<<<(F*BB+255)/256,256,0,stream>>>(h,row_start,counts,csr,w1v,b1,w2r,w2v,b2,z2f,F);
    k_layerB<<<(Ksel*BB+255)/256,256,0,stream>>>(z2f,w3r,w3c,w3v,b3,z3,sums+2*l,Ksel);
    k_layerD<<<(NE*BB+255)/256,256,0,stream>>>(z3,h,sums+2*l,sums+2*LL,gamma,beta,l);
  }

  k_outzero<<<(BB*NN+255)/256,256,0,stream>>>((float*)d_out);
  k_outscatter<<<(NOUT*BB+255)/256,256,0,stream>>>(h,row_start,counts,csr,(float*)d_out);
}

// Round 2
// 258.545 us; speedup vs baseline: 4.3439x; 4.3439x over previous
//
#include <hip/hip_runtime.h>
#include <math.h>

#define NN 10000
#define NE 100000
#define CC 6
#define LL 6
#define BB 16
#define FUNC_LO 100
#define FUNC_HI 9900
#define NOUT 100
#define EPSF 1e-5f
#define NSLOT 64

struct Slot { double s1, s2; double pad[6]; };  // 64B — one cache line per slot

__device__ __forceinline__ float eluf(float x){ return x > 0.0f ? x : expm1f(x); }

// Zero counters/partials, init z3 = b3 broadcast, transpose x (B,N) -> xT (N,B).
__global__ void k_setup(int* __restrict__ counts, int* __restrict__ fill,
                        Slot* __restrict__ part, double* __restrict__ base,
                        float* __restrict__ z3, const float* __restrict__ b3,
                        const float* __restrict__ x, float* __restrict__ xT){
  int tid = blockIdx.x*blockDim.x + threadIdx.x;
  int nt  = gridDim.x*blockDim.x;
  for(int i=tid;i<NN;i+=nt){ counts[i]=0; fill[i]=0; }
  for(int i=tid;i<LL*NSLOT;i+=nt){ part[i].s1 = 0.0; part[i].s2 = 0.0; }
  if(tid < 2) base[tid] = 0.0;
  for(int i=tid;i<NE*BB;i+=nt) z3[i] = b3[i>>4];
  for(int i=tid;i<NN*BB;i+=nt){ int n=i>>4, b=i&15; xT[i] = x[b*NN + n]; }
}

// Histogram of dst; block-reduced BN-sum contribution of non-selected edges
// (src not a func node): z3 stays b3[e] for those, constant across layers.
__global__ __launch_bounds__(256) void k_count(
    const int* __restrict__ dst, int* __restrict__ counts,
    const int* __restrict__ src, const float* __restrict__ b3,
    double* __restrict__ base){
  int e = blockIdx.x*blockDim.x + threadIdx.x;
  float v = 0.0f;
  if(e < NE){
    atomicAdd(&counts[dst[e]], 1);
    int s = src[e];
    if(!(s >= FUNC_LO && s < FUNC_HI)) v = b3[e];
  }
  float s1 = v, s2 = v*v;
  for(int off=32; off; off>>=1){ s1 += __shfl_down(s1, off); s2 += __shfl_down(s2, off); }
  __shared__ float r1[4], r2[4];
  int wid = threadIdx.x>>6;
  if((threadIdx.x & 63)==0){ r1[wid]=s1; r2[wid]=s2; }
  __syncthreads();
  if(threadIdx.x==0){
    double a = (double)(r1[0]+r1[1]+r1[2]+r1[3]) * BB;
    double q = (double)(r2[0]+r2[1]+r2[2]+r2[3]) * BB;
    if(a != 0.0) atomicAdd(&base[0], a);
    if(q != 0.0) atomicAdd(&base[1], q);
  }
}

// Single-block exclusive scan over counts (N=10000), chunked Hillis-Steele.
__global__ void k_scan(const int* __restrict__ counts, int* __restrict__ row_start){
  __shared__ int lds[1024];
  __shared__ int carry;
  if(threadIdx.x==0) carry = 0;
  __syncthreads();
  for(int base=0; base<NN; base+=1024){
    int i = base + (int)threadIdx.x;
    int v = (i<NN) ? counts[i] : 0;
    lds[threadIdx.x] = v; __syncthreads();
    for(int off=1; off<1024; off<<=1){
      int t = (threadIdx.x>=off) ? lds[threadIdx.x-off] : 0;
      __syncthreads();
      lds[threadIdx.x] += t;
      __syncthreads();
    }
    int incl = lds[threadIdx.x];
    if(i<NN) row_start[i] = carry + incl - v;
    __syncthreads();
    if(threadIdx.x==1023) carry += lds[1023];
    __syncthreads();
  }
  if(threadIdx.x==0) row_start[NN] = carry;
}

__global__ void k_fill(const int* __restrict__ dst, const int* __restrict__ row_start,
                       int* __restrict__ fill, int* __restrict__ csr){
  int e = blockIdx.x*blockDim.x + threadIdx.x;
  if(e >= NE) return;
  int n = dst[e];
  int p = row_start[n] + atomicAdd(&fill[n], 1);
  csr[p] = e;
}

// h[e][b] = x[b][src[e]]  (via transposed xT for coalescing)
__global__ void k_hinit(const int* __restrict__ src, const float* __restrict__ xT,
                        float* __restrict__ h){
  int idx = blockIdx.x*blockDim.x + threadIdx.x;
  if(idx >= NE*BB) return;
  int e = idx>>4, b = idx&15;
  h[idx] = xT[src[e]*BB + b];
}

// Fused: z1 = CSR-gather(h)*W1 + b1 ; ELU ; z2 = z1 * W2block + b2 ; ELU.
// One 16-lane group per func node; lane = batch index. z1 lives in registers.
__global__ __launch_bounds__(256) void k_layerA(
    const float* __restrict__ h, const int* __restrict__ row_start,
    const int* __restrict__ counts, const int* __restrict__ csr,
    const float* __restrict__ w1v, const float* __restrict__ b1,
    const int* __restrict__ w2r, const float* __restrict__ w2v,
    const float* __restrict__ b2, float* __restrict__ z2f, int F){
  int t = blockIdx.x*256 + (int)threadIdx.x;
  int fi = t>>4, b = t&15;
  if(fi >= F) return;
  int n = w2r[fi*36] / CC;   // func node id from w2 structure
  float acc[CC];
  #pragma unroll
  for(int i=0;i<CC;i++) acc[i] = b1[n*CC+i];
  int beg = row_start[n], end = beg + counts[n];
  for(int p=beg; p<end; ++p){
    int e = csr[p];
    float hv = h[e*BB + b];
    const float* w = &w1v[e*CC];
    #pragma unroll
    for(int i=0;i<CC;i++) acc[i] += hv * w[i];
  }
  #pragma unroll
  for(int i=0;i<CC;i++) acc[i] = eluf(acc[i]);
  const float* W2 = &w2v[fi*36];
  #pragma unroll
  for(int j=0;j<CC;j++){
    float o = b2[n*CC+j];
    #pragma unroll
    for(int i=0;i<CC;i++) o += acc[i] * W2[i*CC + j];
    z2f[(fi*CC + j)*BB + b] = eluf(o);
  }
}

// z3[e] = b3[e] + sum_i z2f[src-block] * w3 ; BN partial sums to spread slots.
__global__ __launch_bounds__(256) void k_layerB(
    const float* __restrict__ z2f, const int* __restrict__ w3r,
    const int* __restrict__ w3c, const float* __restrict__ w3v,
    const float* __restrict__ b3, float* __restrict__ z3,
    Slot* __restrict__ part, int Ksel){
  int t = blockIdx.x*256 + (int)threadIdx.x;
  int k = t>>4, b = t&15;
  float val = 0.0f;
  if(k < Ksel){
    int e = w3c[k*CC];
    int s = w3r[k*CC] / CC;
    int fi = s - FUNC_LO;
    float o = b3[e];
    #pragma unroll
    for(int i=0;i<CC;i++) o += z2f[(fi*CC + i)*BB + b] * w3v[k*CC + i];
    z3[e*BB + b] = o;
    val = o;
  }
  float s1 = val, s2 = val*val;
  for(int off=32; off; off>>=1){ s1 += __shfl_down(s1, off); s2 += __shfl_down(s2, off); }
  __shared__ float r1[4], r2[4];
  int wid = threadIdx.x>>6;
  if((threadIdx.x & 63)==0){ r1[wid]=s1; r2[wid]=s2; }
  __syncthreads();
  if(threadIdx.x==0){
    double a = (double)(r1[0]+r1[1]+r1[2]+r1[3]);
    double q = (double)(r2[0]+r2[1]+r2[2]+r2[3]);
    Slot* sl = &part[blockIdx.x & (NSLOT-1)];
    atomicAdd(&sl->s1, a);
    atomicAdd(&sl->s2, q);
  }
}

// BN normalize + residual, in place on h. Each block first reduces the 64
// partial slots (4KB, L2-hot) to the global sums — no extra launch needed.
__global__ __launch_bounds__(256) void k_layerD(
    const float* __restrict__ z3, float* __restrict__ h,
    const Slot* __restrict__ part, const double* __restrict__ base,
    const float* __restrict__ gamma, const float* __restrict__ beta, int l){
  __shared__ double sh1[NSLOT], sh2[NSLOT];
  int t = threadIdx.x;
  if(t < NSLOT){ sh1[t] = part[t].s1; sh2[t] = part[t].s2; }
  __syncthreads();
  for(int off=NSLOT/2; off; off>>=1){
    if(t < off){ sh1[t] += sh1[t+off]; sh2[t] += sh2[t+off]; }
    __syncthreads();
  }
  double S  = sh1[0] + base[0];
  double SS = sh2[0] + base[1];
  const double cnt = (double)NE * (double)BB;
  double md = S / cnt;
  double vd = SS / cnt - md*md;
  float m   = (float)md;
  float inv = (float)(1.0 / sqrt(vd + (double)EPSF));
  float g = gamma[l], be = beta[l];
  int idx = blockIdx.x*256 + t;
  if(idx < NE*BB) h[idx] += (z3[idx] - m) * inv * g + be;
}

__global__ void k_outzero(float* __restrict__ out){
  int idx = blockIdx.x*blockDim.x + threadIdx.x;
  if(idx < BB*NN) out[idx] = 0.0f;
}

// out[b][n] = (sum over in-edges of h)/L for output nodes n in [9900,10000).
__global__ void k_outscatter(const float* __restrict__ h, const int* __restrict__ row_start,
                             const int* __restrict__ counts, const int* __restrict__ csr,
                             float* __restrict__ out){
  int t = blockIdx.x*blockDim.x + threadIdx.x;
  if(t >= NOUT*BB) return;
  int g = t>>4, b = t&15;
  int n = FUNC_HI + g;
  float acc = 0.0f;
  int beg = row_start[n], end = beg + counts[n];
  for(int p=beg; p<end; ++p) acc += h[csr[p]*BB + b];
  out[b*NN + n] = acc * (1.0f/(float)LL);
}

extern "C" void kernel_launch(void* const* d_in, const int* in_sizes, int n_in,
                              void* d_out, int out_size, void* d_ws, size_t ws_size,
                              hipStream_t stream){
  const float* x    = (const float*)d_in[0];
  const int*   src  = (const int*)  d_in[1];
  const int*   dst  = (const int*)  d_in[2];
  const float* w1v  = (const float*)d_in[6];
  const float* b1   = (const float*)d_in[7];
  const int*   w2r  = (const int*)  d_in[8];
  const float* w2v  = (const float*)d_in[10];
  const float* b2   = (const float*)d_in[11];
  const int*   w3r  = (const int*)  d_in[12];
  const int*   w3c  = (const int*)  d_in[13];
  const float* w3v  = (const float*)d_in[14];
  const float* b3   = (const float*)d_in[15];
  const float* gamma= (const float*)d_in[16];
  const float* beta = (const float*)d_in[17];
  int F    = in_sizes[8]  / 36;
  int Ksel = in_sizes[12] / CC;

  char* ws = (char*)d_ws;
  size_t off = 0;
  auto alloc = [&](size_t bytes)->char*{
    char* p = ws + off;
    off = (off + bytes + 255) & ~(size_t)255;
    return p;
  };
  int*    row_start = (int*)   alloc((NN+1)*sizeof(int));
  int*    counts    = (int*)   alloc(NN*sizeof(int));
  int*    fill      = (int*)   alloc(NN*sizeof(int));
  int*    csr       = (int*)   alloc(NE*sizeof(int));
  float*  xT        = (float*) alloc((size_t)NN*BB*sizeof(float));
  float*  h         = (float*) alloc((size_t)NE*BB*sizeof(float));
  float*  z2f       = (float*) alloc((size_t)F*CC*BB*sizeof(float));
  float*  z3        = (float*) alloc((size_t)NE*BB*sizeof(float));
  Slot*   part      = (Slot*)  alloc((size_t)LL*NSLOT*sizeof(Slot));
  double* base      = (double*)alloc(2*sizeof(double));
  (void)ws_size; (void)n_in; (void)out_size;

  k_setup<<<1024,256,0,stream>>>(counts,fill,part,base,z3,b3,x,xT);
  k_count<<<(NE+255)/256,256,0,stream>>>(dst,counts,src,b3,base);
  k_scan<<<1,1024,0,stream>>>(counts,row_start);
  k_fill<<<(NE+255)/256,256,0,stream>>>(dst,row_start,fill,csr);
  k_hinit<<<(NE*BB+255)/256,256,0,stream>>>(src,xT,h);

  for(int l=0;l<LL;l++){
    k_layerA<<<(F*BB+255)/256,256,0,stream>>>(h,row_start,counts,csr,w1v,b1,w2r,w2v,b2,z2f,F);
    k_layerB<<<(Ksel*BB+255)/256,256,0,stream>>>(z2f,w3r,w3c,w3v,b3,z3,part+l*NSLOT,Ksel);
    k_layerD<<<(NE*BB+255)/256,256,0,stream>>>(z3,h,part+l*NSLOT,base,gamma,beta,l);
  }

  k_outzero<<<(BB*NN+255)/256,256,0,stream>>>((float*)d_out);
  k_outscatter<<<(NOUT*BB+255)/256,256,0,stream>>>(h,row_start,counts,csr,(float*)d_out);
}

// Round 3
// 228.557 us; speedup vs baseline: 4.9139x; 1.1312x over previous
//
#include <hip/hip_runtime.h>
#include <math.h>

#define NN 10000
#define NE 100000
#define CC 6
#define LL 6
#define BB 16
#define FUNC_LO 100
#define FUNC_HI 9900
#define NOUT 100
#define EPSF 1e-5f
#define NSLOT 64

struct Slot { double s1, s2; double pad[6]; };  // 64B — one cache line per slot

__device__ __forceinline__ float eluf(float x){ return x > 0.0f ? x : expm1f(x); }

// Zero counters/partials, transpose x (B,N) -> xT (N,B). No z3 init: layerD
// reconstructs z3 = b3[e] for non-selected edges from src[e] on the fly.
__global__ void k_setup(int* __restrict__ counts, int* __restrict__ fill,
                        Slot* __restrict__ part, double* __restrict__ base,
                        const float* __restrict__ x, float* __restrict__ xT){
  int tid = blockIdx.x*blockDim.x + threadIdx.x;
  int nt  = gridDim.x*blockDim.x;
  for(int i=tid;i<NN;i+=nt){ counts[i]=0; fill[i]=0; }
  for(int i=tid;i<LL*NSLOT;i+=nt){ part[i].s1 = 0.0; part[i].s2 = 0.0; }
  if(tid < 2) base[tid] = 0.0;
  for(int i=tid;i<NN*BB;i+=nt){ int n=i>>4, b=i&15; xT[i] = x[b*NN + n]; }
}

// Histogram of dst; block-reduced BN base sums (non-func-src edges keep
// z3 = b3[e] every layer); fused h init: h[e][b] = xT[src[e]][b].
__global__ __launch_bounds__(256) void k_count(
    const int* __restrict__ dst, int* __restrict__ counts,
    const int* __restrict__ src, const float* __restrict__ b3,
    double* __restrict__ base, const float* __restrict__ xT,
    float* __restrict__ h){
  int e = blockIdx.x*blockDim.x + threadIdx.x;
  float v = 0.0f;
  if(e < NE){
    atomicAdd(&counts[dst[e]], 1);
    int s = src[e];
    if(!(s >= FUNC_LO && s < FUNC_HI)) v = b3[e];
  }
  float s1 = v, s2 = v*v;
  for(int off=32; off; off>>=1){ s1 += __shfl_down(s1, off); s2 += __shfl_down(s2, off); }
  __shared__ float r1[4], r2[4];
  int wid = threadIdx.x>>6;
  if((threadIdx.x & 63)==0){ r1[wid]=s1; r2[wid]=s2; }
  __syncthreads();
  if(threadIdx.x==0){
    double a = (double)(r1[0]+r1[1]+r1[2]+r1[3]) * BB;
    double q = (double)(r2[0]+r2[1]+r2[2]+r2[3]) * BB;
    if(a != 0.0) atomicAdd(&base[0], a);
    if(q != 0.0) atomicAdd(&base[1], q);
  }
  // fused h-init, block-strided
  int tid = blockIdx.x*blockDim.x + threadIdx.x;
  int nt  = gridDim.x*blockDim.x;
  for(int i=tid;i<NE*BB;i+=nt) h[i] = xT[src[i>>4]*BB + (i&15)];
}

// Single-block scan, 1024 threads x 10 nodes each: register-serial partial
// sums + one 10-step LDS Hillis-Steele (~20 barriers total, not 200).
__global__ __launch_bounds__(1024) void k_scan(const int* __restrict__ counts,
                                               int* __restrict__ row_start){
  __shared__ int ssum[1024];
  int t = threadIdx.x;
  int base = t*10;
  int loc[10]; int s = 0;
  #pragma unroll
  for(int k=0;k<10;k++){ int i=base+k; int c=(i<NN)?counts[i]:0; loc[k]=s; s+=c; }
  ssum[t] = s; __syncthreads();
  for(int off=1; off<1024; off<<=1){
    int v = (t>=off) ? ssum[t-off] : 0;
    __syncthreads();
    ssum[t] += v;
    __syncthreads();
  }
  int excl = ssum[t] - s;
  #pragma unroll
  for(int k=0;k<10;k++){ int i=base+k; if(i<NN) row_start[i] = excl + loc[k]; }
  if(t==1023) row_start[NN] = ssum[1023];
}

__global__ void k_fill(const int* __restrict__ dst, const int* __restrict__ row_start,
                       int* __restrict__ fill, int* __restrict__ csr){
  int e = blockIdx.x*blockDim.x + threadIdx.x;
  if(e >= NE) return;
  int n = dst[e];
  int p = row_start[n] + atomicAdd(&fill[n], 1);
  csr[p] = e;
}

// Fused: z1 = CSR-gather(h)*W1 + b1 ; ELU ; z2 = z1 * W2block + b2 ; ELU.
// One 16-lane group per func node; lane = batch index. z1 lives in registers.
__global__ __launch_bounds__(256) void k_layerA(
    const float* __restrict__ h, const int* __restrict__ row_start,
    const int* __restrict__ csr,
    const float* __restrict__ w1v, const float* __restrict__ b1,
    const int* __restrict__ w2r, const float* __restrict__ w2v,
    const float* __restrict__ b2, float* __restrict__ z2f, int F){
  int t = blockIdx.x*256 + (int)threadIdx.x;
  int fi = t>>4, b = t&15;
  if(fi >= F) return;
  int n = w2r[fi*36] / CC;   // func node id from w2 structure
  float acc[CC];
  #pragma unroll
  for(int i=0;i<CC;i++) acc[i] = b1[n*CC+i];
  int beg = row_start[n], end = row_start[n+1];
  for(int p=beg; p<end; ++p){
    int e = csr[p];
    float hv = h[e*BB + b];
    const float* w = &w1v[e*CC];
    #pragma unroll
    for(int i=0;i<CC;i++) acc[i] += hv * w[i];
  }
  #pragma unroll
  for(int i=0;i<CC;i++) acc[i] = eluf(acc[i]);
  const float* W2 = &w2v[fi*36];
  #pragma unroll
  for(int j=0;j<CC;j++){
    float o = b2[n*CC+j];
    #pragma unroll
    for(int i=0;i<CC;i++) o += acc[i] * W2[i*CC + j];
    z2f[(fi*CC + j)*BB + b] = eluf(o);
  }
}

// z3[e] = b3[e] + sum_i z2f[src-block] * w3 ; BN partial sums to spread slots.
__global__ __launch_bounds__(256) void k_layerB(
    const float* __restrict__ z2f, const int* __restrict__ w3r,
    const int* __restrict__ w3c, const float* __restrict__ w3v,
    const float* __restrict__ b3, float* __restrict__ z3,
    Slot* __restrict__ part, int Ksel){
  int t = blockIdx.x*256 + (int)threadIdx.x;
  int k = t>>4, b = t&15;
  float val = 0.0f;
  if(k < Ksel){
    int e = w3c[k*CC];
    int s = w3r[k*CC] / CC;
    int fi = s - FUNC_LO;
    float o = b3[e];
    #pragma unroll
    for(int i=0;i<CC;i++) o += z2f[(fi*CC + i)*BB + b] * w3v[k*CC + i];
    z3[e*BB + b] = o;
    val = o;
  }
  float s1 = val, s2 = val*val;
  for(int off=32; off; off>>=1){ s1 += __shfl_down(s1, off); s2 += __shfl_down(s2, off); }
  __shared__ float r1[4], r2[4];
  int wid = threadIdx.x>>6;
  if((threadIdx.x & 63)==0){ r1[wid]=s1; r2[wid]=s2; }
  __syncthreads();
  if(threadIdx.x==0){
    double a = (double)(r1[0]+r1[1]+r1[2]+r1[3]);
    double q = (double)(r2[0]+r2[1]+r2[2]+r2[3]);
    Slot* sl = &part[blockIdx.x & (NSLOT-1)];
    atomicAdd(&sl->s1, a);
    atomicAdd(&sl->s2, q);
  }
}

// BN normalize + residual, in place on h, float4 (4 threads per edge).
// Non-selected edges (src not func): z3 == b3[e], never materialized.
__global__ __launch_bounds__(256) void k_layerD(
    const float4* __restrict__ z3, float4* __restrict__ h,
    const int* __restrict__ src, const float* __restrict__ b3,
    const Slot* __restrict__ part, const double* __restrict__ base,
    const float* __restrict__ gamma, const float* __restrict__ beta, int l){
  __shared__ double sh1[NSLOT], sh2[NSLOT];
  int t = threadIdx.x;
  if(t < NSLOT){ sh1[t] = part[t].s1; sh2[t] = part[t].s2; }
  __syncthreads();
  for(int off=NSLOT/2; off; off>>=1){
    if(t < off){ sh1[t] += sh1[t+off]; sh2[t] += sh2[t+off]; }
    __syncthreads();
  }
  double S  = sh1[0] + base[0];
  double SS = sh2[0] + base[1];
  const double cnt = (double)NE * (double)BB;
  double md = S / cnt;
  double vd = SS / cnt - md*md;
  float m   = (float)md;
  float inv = (float)(1.0 / sqrt(vd + (double)EPSF));
  float g = gamma[l], be = beta[l];
  int idx = blockIdx.x*256 + t;            // over NE*4 float4's
  if(idx < NE*4){
    int e = idx>>2;
    int s = src[e];
    float4 z;
    if(s >= FUNC_LO && s < FUNC_HI){
      z = z3[idx];
    } else {
      float v = b3[e]; z = make_float4(v,v,v,v);
    }
    float4 hv = h[idx];
    hv.x += (z.x - m) * inv * g + be;
    hv.y += (z.y - m) * inv * g + be;
    hv.z += (z.z - m) * inv * g + be;
    hv.w += (z.w - m) * inv * g + be;
    h[idx] = hv;
  }
}

// out[b][n] = (sum over in-edges of h)/L for output nodes, 0 elsewhere.
// idx = b*NN + n so zero-writes are fully coalesced.
__global__ __launch_bounds__(256) void k_out(
    const float* __restrict__ h, const int* __restrict__ row_start,
    const int* __restrict__ csr, float* __restrict__ out){
  int idx = blockIdx.x*blockDim.x + threadIdx.x;
  if(idx >= BB*NN) return;
  int b = idx / NN, n = idx - b*NN;
  float acc = 0.0f;
  if(n >= FUNC_HI){
    int beg = row_start[n], end = row_start[n+1];
    for(int p=beg; p<end; ++p) acc += h[csr[p]*BB + b];
    acc *= (1.0f/(float)LL);
  }
  out[idx] = acc;
}

extern "C" void kernel_launch(void* const* d_in, const int* in_sizes, int n_in,
                              void* d_out, int out_size, void* d_ws, size_t ws_size,
                              hipStream_t stream){
  const float* x    = (const float*)d_in[0];
  const int*   src  = (const int*)  d_in[1];
  const int*   dst  = (const int*)  d_in[2];
  const float* w1v  = (const float*)d_in[6];
  const float* b1   = (const float*)d_in[7];
  const int*   w2r  = (const int*)  d_in[8];
  const float* w2v  = (const float*)d_in[10];
  const float* b2   = (const float*)d_in[11];
  const int*   w3r  = (const int*)  d_in[12];
  const int*   w3c  = (const int*)  d_in[13];
  const float* w3v  = (const float*)d_in[14];
  const float* b3   = (const float*)d_in[15];
  const float* gamma= (const float*)d_in[16];
  const float* beta = (const float*)d_in[17];
  int F    = in_sizes[8]  / 36;
  int Ksel = in_sizes[12] / CC;

  char* ws = (char*)d_ws;
  size_t off = 0;
  auto alloc = [&](size_t bytes)->char*{
    char* p = ws + off;
    off = (off + bytes + 255) & ~(size_t)255;
    return p;
  };
  int*    row_start = (int*)   alloc((NN+1)*sizeof(int));
  int*    counts    = (int*)   alloc(NN*sizeof(int));
  int*    fill      = (int*)   alloc(NN*sizeof(int));
  int*    csr       = (int*)   alloc(NE*sizeof(int));
  float*  xT        = (float*) alloc((size_t)NN*BB*sizeof(float));
  float*  h         = (float*) alloc((size_t)NE*BB*sizeof(float));
  float*  z2f       = (float*) alloc((size_t)F*CC*BB*sizeof(float));
  float*  z3        = (float*) alloc((size_t)NE*BB*sizeof(float));
  Slot*   part      = (Slot*)  alloc((size_t)LL*NSLOT*sizeof(Slot));
  double* base      = (double*)alloc(2*sizeof(double));
  (void)ws_size; (void)n_in; (void)out_size;

  k_setup<<<256,256,0,stream>>>(counts,fill,part,base,x,xT);
  k_count<<<(NE+255)/256,256,0,stream>>>(dst,counts,src,b3,base,xT,h);
  k_scan<<<1,1024,0,stream>>>(counts,row_start);
  k_fill<<<(NE+255)/256,256,0,stream>>>(dst,row_start,fill,csr);

  for(int l=0;l<LL;l++){
    k_layerA<<<(F*BB+255)/256,256,0,stream>>>(h,row_start,csr,w1v,b1,w2r,w2v,b2,z2f,F);
    k_layerB<<<(Ksel*BB+255)/256,256,0,stream>>>(z2f,w3r,w3c,w3v,b3,z3,part+l*NSLOT,Ksel);
    k_layerD<<<(NE*4+255)/256,256,0,stream>>>((const float4*)z3,(float4*)h,src,b3,
                                              part+l*NSLOT,base,gamma,beta,l);
  }

  k_out<<<(BB*NN+255)/256,256,0,stream>>>(h,row_start,csr,(float*)d_out);
}